// Round 2
// baseline (24661.877 us; speedup 1.0000x reference)
//
#include <hip/hip_runtime.h>

typedef short bf16x8 __attribute__((ext_vector_type(8)));
typedef float f32x4 __attribute__((ext_vector_type(4)));

__device__ __forceinline__ unsigned pack2bf(float a, float b) {
  union { float f; unsigned u; } x, y;
  x.f = a; y.f = b;
  unsigned ra = (x.u + 0x7FFFu + ((x.u >> 16) & 1u)) >> 16;
  unsigned rb = (y.u + 0x7FFFu + ((y.u >> 16) & 1u)) & 0xFFFF0000u;
  return ra | rb;
}
__device__ __forceinline__ unsigned short bfu(float f) {
  union { float f; unsigned u; } v; v.f = f;
  return (unsigned short)((v.u + 0x7FFFu + ((v.u >> 16) & 1u)) >> 16);
}
__device__ __forceinline__ float sigf(float x) { return 1.f / (1.f + __expf(-x)); }

#define KB 64
#define LDSP 72

// ---------------- xg GEMM (unchanged from round 1, verified) ----------------
__global__ __launch_bounds__(256) void gemm_bt(
    const float* __restrict__ A0, size_t a_bstride,
    const float* __restrict__ W,
    const float* __restrict__ bias,
    float* __restrict__ out, size_t o_bstride,
    int Mvalid)
{
  __shared__ unsigned short As[64][LDSP];
  __shared__ unsigned short Bs[64][LDSP];
  const int tid = threadIdx.x;
  const int g0 = blockIdx.x * 64;
  const float* Ab = A0 + (size_t)blockIdx.y * a_bstride;
  float* outb = out + (size_t)blockIdx.y * o_bstride;

  const int srow = tid >> 2;
  const int scol = (tid & 3) << 4;
  const int wv = tid >> 6;
  const int lane = tid & 63;
  const int wr = wv >> 1, wc = wv & 1;
  const int lrow = lane & 15;
  const int lk = (lane >> 4) << 3;

  f32x4 acc[2][2];
#pragma unroll
  for (int i = 0; i < 2; ++i)
#pragma unroll
    for (int j = 0; j < 2; ++j)
      acc[i][j] = (f32x4){0.f, 0.f, 0.f, 0.f};

  const float* Aptr = Ab + (size_t)srow * 768 + scol;
  const float* Bptr = W + ((size_t)(g0 + srow)) * 768 + scol;
  const bool aval = srow < Mvalid;

  for (int k0 = 0; k0 < 768; k0 += KB) {
    uint4 ua0, ua1, ub0, ub1;
    if (aval) {
      const float4* qa = (const float4*)(Aptr + k0);
      float4 f0 = qa[0], f1 = qa[1], f2 = qa[2], f3 = qa[3];
      ua0 = make_uint4(pack2bf(f0.x, f0.y), pack2bf(f0.z, f0.w),
                       pack2bf(f1.x, f1.y), pack2bf(f1.z, f1.w));
      ua1 = make_uint4(pack2bf(f2.x, f2.y), pack2bf(f2.z, f2.w),
                       pack2bf(f3.x, f3.y), pack2bf(f3.z, f3.w));
    } else {
      ua0 = make_uint4(0u, 0u, 0u, 0u);
      ua1 = ua0;
    }
    {
      const float4* qb = (const float4*)(Bptr + k0);
      float4 f0 = qb[0], f1 = qb[1], f2 = qb[2], f3 = qb[3];
      ub0 = make_uint4(pack2bf(f0.x, f0.y), pack2bf(f0.z, f0.w),
                       pack2bf(f1.x, f1.y), pack2bf(f1.z, f1.w));
      ub1 = make_uint4(pack2bf(f2.x, f2.y), pack2bf(f2.z, f2.w),
                       pack2bf(f3.x, f3.y), pack2bf(f3.z, f3.w));
    }
    __syncthreads();
    *(uint4*)&As[srow][scol] = ua0;
    *(uint4*)&As[srow][scol + 8] = ua1;
    *(uint4*)&Bs[srow][scol] = ub0;
    *(uint4*)&Bs[srow][scol + 8] = ub1;
    __syncthreads();
#pragma unroll
    for (int kh = 0; kh < 2; ++kh) {
      bf16x8 a0 = *(const bf16x8*)&As[32 * wr + lrow][32 * kh + lk];
      bf16x8 a1 = *(const bf16x8*)&As[32 * wr + 16 + lrow][32 * kh + lk];
      bf16x8 b0 = *(const bf16x8*)&Bs[32 * wc + lrow][32 * kh + lk];
      bf16x8 b1 = *(const bf16x8*)&Bs[32 * wc + 16 + lrow][32 * kh + lk];
      acc[0][0] = __builtin_amdgcn_mfma_f32_16x16x32_bf16(a0, b0, acc[0][0], 0, 0, 0);
      acc[0][1] = __builtin_amdgcn_mfma_f32_16x16x32_bf16(a0, b1, acc[0][1], 0, 0, 0);
      acc[1][0] = __builtin_amdgcn_mfma_f32_16x16x32_bf16(a1, b0, acc[1][0], 0, 0, 0);
      acc[1][1] = __builtin_amdgcn_mfma_f32_16x16x32_bf16(a1, b1, acc[1][1], 0, 0, 0);
    }
  }

  const int lgrp = lane >> 4;
#pragma unroll
  for (int fr = 0; fr < 2; ++fr)
#pragma unroll
    for (int fc = 0; fc < 2; ++fc)
#pragma unroll
      for (int j = 0; j < 4; ++j) {
        int m = 32 * wr + 16 * fr + lgrp * 4 + j;
        int n = 32 * wc + 16 * fc + lrow;
        if (m < Mvalid)
          outb[(size_t)m * 2304 + g0 + n] = acc[fr][fc][j] + bias[g0 + n];
      }
}

// ---------------- persistent recurrent chunk kernel ----------------
#define NWG 48
#define HS 16
#define EPS 1e-5f
#define INV768 (1.0f / 768.0f)

__device__ __forceinline__ void gbar(unsigned* ctr, unsigned target) {
  __syncthreads();
  if (threadIdx.x == 0) {
    __hip_atomic_fetch_add(ctr, 1u, __ATOMIC_RELEASE, __HIP_MEMORY_SCOPE_AGENT);
    while (__hip_atomic_load(ctr, __ATOMIC_ACQUIRE, __HIP_MEMORY_SCOPE_AGENT) < target)
      __builtin_amdgcn_s_sleep(1);
  }
  __syncthreads();
}

__global__ __launch_bounds__(256, 1) void gru_chunk(
    const float* __restrict__ Whh, const float* __restrict__ bhh,
    const float* __restrict__ lw, const float* __restrict__ lb,
    const float* __restrict__ xg,    // [64][TC][2304]
    const float* __restrict__ res,   // residual [64][512][768]
    float* __restrict__ seq,         // output seq [64][512][768]
    int t0, int TC,
    const float* __restrict__ hin,   // [64][768] f32
    float* __restrict__ hstate,      // [64][768] f32
    unsigned short* __restrict__ hbf, // tiled [96][64][8] bf16
    float* __restrict__ stats1,      // [NWG][256]
    float* __restrict__ stats2,      // [NWG][128]
    unsigned* __restrict__ barctr,
    float* __restrict__ hfin, int lastflag)
{
  __shared__ unsigned short Wl[48][776];   // padded: 1552B rows -> 2-way-free banks
  __shared__ float S1[64][16], S2[64][16], HN[64][16];
  __shared__ float statsl[384];            // [0..255]: ln1 sums, [256..383]: ln2
  __shared__ float bhl[48], lwl[48], lbl[48];

  const int wg = blockIdx.x;
  const int tid = threadIdx.x;
  const int i0 = wg * HS;
  const int lane = tid & 63;
  const int w = tid >> 6;       // wave 0..3
  const int la = lane & 15;
  const int lb16 = lane >> 4;
  const int ii = tid & 15;      // update-phase h index
  const int bq = tid >> 4;      // update-phase batch base

  // ---- init: stage W_hh slice (48 rows) into LDS as bf16 ----
  for (int lr = 0; lr < 48; ++lr) {
    const float* src = Whh + ((size_t)((lr >> 4) * 768 + i0 + (lr & 15))) * 768;
    for (int c = tid; c < 768; c += 256) Wl[lr][c] = bfu(src[c]);
  }
  if (tid < 48) {
    int ty = tid >> 4, iq = tid & 15;
    bhl[tid] = bhh[ty * 768 + i0 + iq];
    lwl[tid] = lw[ty * 768 + i0 + iq];
    lbl[tid] = lb[ty * 768 + i0 + iq];
  }
  float hreg[4];
#pragma unroll
  for (int q = 0; q < 4; ++q) {
    int b = bq + 16 * q;
    hreg[q] = hin[(size_t)b * 768 + i0 + ii];
  }
  if (t0 == 0) {
    int gi = i0 + ii;
#pragma unroll
    for (int q = 0; q < 4; ++q) {
      int b = bq + 16 * q;
      hbf[((gi >> 3) * 64 + b) * 8 + (gi & 7)] = bfu(hreg[q]);
    }
  }
  unsigned epoch = 1;
  gbar(barctr, epoch * NWG);

  for (int tt = 0; tt < TC; ++tt) {
    // ---- phase A: hg = h @ Whh^T for our 48 gate rows, all 64 batches ----
    f32x4 acc0 = (f32x4){0.f, 0.f, 0.f, 0.f}, acc1 = acc0, acc2 = acc0;
    const int arow = 16 * w + la;
#pragma unroll 4
    for (int kk = 0; kk < 24; ++kk) {
      bf16x8 af = *(const bf16x8*)(hbf + (size_t)(((kk * 4 + lb16) * 64) + arow) * 8);
      bf16x8 b0 = *(const bf16x8*)&Wl[la][kk * 32 + lb16 * 8];
      bf16x8 b1 = *(const bf16x8*)&Wl[16 + la][kk * 32 + lb16 * 8];
      bf16x8 b2 = *(const bf16x8*)&Wl[32 + la][kk * 32 + lb16 * 8];
      acc0 = __builtin_amdgcn_mfma_f32_16x16x32_bf16(af, b0, acc0, 0, 0, 0);
      acc1 = __builtin_amdgcn_mfma_f32_16x16x32_bf16(af, b1, acc1, 0, 0, 0);
      acc2 = __builtin_amdgcn_mfma_f32_16x16x32_bf16(af, b2, acc2, 0, 0, 0);
    }
    // stage s1/s2/hn to LDS + LN1 partial sums
#pragma unroll
    for (int j = 0; j < 4; ++j) {
      int b = 16 * w + 4 * lb16 + j;
      const float* xr = xg + ((size_t)b * TC + tt) * 2304 + i0;
      float s1 = acc0[j] + bhl[la] + xr[la];
      float s2 = acc1[j] + bhl[16 + la] + xr[768 + la];
      float hn = acc2[j] + bhl[32 + la];
      S1[b][la] = s1; S2[b][la] = s2; HN[b][la] = hn;
      float p0 = s1, p1 = s1 * s1, p2 = s2, p3 = s2 * s2;
#pragma unroll
      for (int off = 1; off < 16; off <<= 1) {
        p0 += __shfl_xor(p0, off, 16);
        p1 += __shfl_xor(p1, off, 16);
        p2 += __shfl_xor(p2, off, 16);
        p3 += __shfl_xor(p3, off, 16);
      }
      float pv = (la == 0) ? p0 : (la == 1) ? p1 : (la == 2) ? p2 : p3;
      if (la < 4) stats1[wg * 256 + b * 4 + la] = pv;
    }
    ++epoch; gbar(barctr, epoch * NWG);

    // ---- combine LN1 stats ----
    {
      float s = 0.f;
#pragma unroll 8
      for (int ww = 0; ww < NWG; ++ww) s += stats1[ww * 256 + tid];
      statsl[tid] = s;
    }
    __syncthreads();

    // ---- phase B: r, z, m, LN2 partials ----
    float zq[4], mq[4];
#pragma unroll
    for (int q = 0; q < 4; ++q) {
      int b = bq + 16 * q;
      float mu1 = statsl[b * 4 + 0] * INV768;
      float rs1 = rsqrtf(statsl[b * 4 + 1] * INV768 - mu1 * mu1 + EPS);
      float mu2 = statsl[b * 4 + 2] * INV768;
      float rs2 = rsqrtf(statsl[b * 4 + 3] * INV768 - mu2 * mu2 + EPS);
      float r = sigf((S1[b][ii] - mu1) * rs1 * lwl[ii] + lbl[ii]);
      zq[q]  = sigf((S2[b][ii] - mu2) * rs2 * lwl[16 + ii] + lbl[16 + ii]);
      float xn = xg[((size_t)b * TC + tt) * 2304 + 1536 + i0 + ii];
      mq[q] = xn + r * HN[b][ii];
      float p0 = mq[q], p1 = mq[q] * mq[q];
#pragma unroll
      for (int off = 1; off < 16; off <<= 1) {
        p0 += __shfl_xor(p0, off, 16);
        p1 += __shfl_xor(p1, off, 16);
      }
      if (ii < 2) stats2[wg * 128 + b * 2 + ii] = (ii == 0) ? p0 : p1;
    }
    ++epoch; gbar(barctr, epoch * NWG);

    if (tid < 128) {
      float s = 0.f;
#pragma unroll 8
      for (int ww = 0; ww < NWG; ++ww) s += stats2[ww * 128 + tid];
      statsl[256 + tid] = s;
    }
    __syncthreads();

    // ---- phase C: n, h update, outputs ----
    const int gt = t0 + tt;
    const int gi = i0 + ii;
#pragma unroll
    for (int q = 0; q < 4; ++q) {
      int b = bq + 16 * q;
      float mum = statsl[256 + b * 2] * INV768;
      float rsm = rsqrtf(statsl[256 + b * 2 + 1] * INV768 - mum * mum + EPS);
      float n = tanhf((mq[q] - mum) * rsm * lwl[32 + ii] + lbl[32 + ii]);
      float hnew = (1.f - zq[q]) * n + zq[q] * hreg[q];
      hreg[q] = hnew;
      size_t o = ((size_t)b * 512 + gt) * 768 + gi;
      float rv = res[o];
      seq[o] = hnew + rv;
      hbf[((gi >> 3) * 64 + b) * 8 + (gi & 7)] = bfu(hnew);
    }
    ++epoch; gbar(barctr, epoch * NWG);
  }

  // ---- chunk end: persist h, emit final h ----
#pragma unroll
  for (int q = 0; q < 4; ++q) {
    int b = bq + 16 * q;
    hstate[(size_t)b * 768 + i0 + ii] = hreg[q];
    if (lastflag) hfin[(size_t)b * 768 + i0 + ii] = hreg[q];
  }
}

extern "C" void kernel_launch(void* const* d_in, const int* in_sizes, int n_in,
                              void* d_out, int out_size, void* d_ws, size_t ws_size,
                              hipStream_t stream) {
  const float* x    = (const float*)d_in[0];
  const float* h0   = (const float*)d_in[1];
  const float* w_ih = (const float*)d_in[2];
  const float* b_ih = (const float*)d_in[3];
  const float* w_hh = (const float*)d_in[4];
  const float* b_hh = (const float*)d_in[5];
  const float* lnw  = (const float*)d_in[6];
  const float* lnb  = (const float*)d_in[7];
  float* out = (float*)d_out;

  const int B = 64, T = 512, H = 768, G = 2304, L = 2;

  const size_t fixed = 4096 + 98304 + 196608 + 49152 + 24576;
  int CHUNK = 64;
  for (;;) {
    size_t need = fixed + (size_t)B * CHUNK * G * 4;
    if (need <= ws_size || CHUNK == 8) break;
    CHUNK >>= 1;
  }

  unsigned* barctr = (unsigned*)d_ws;
  unsigned short* hbf = (unsigned short*)((char*)d_ws + 4096);
  float* hstate = (float*)((char*)d_ws + 4096 + 98304);
  float* stats1 = hstate + 49152;
  float* stats2 = stats1 + 12288;
  float* xg     = stats2 + 6144;

  hipMemsetAsync(barctr, 0, 4096, stream);

  float* seq  = out;
  float* hfin = out + (size_t)B * T * H;
  const int NCH = T / CHUNK;

  for (int l = 0; l < L; ++l) {
    const float* Wih = w_ih + (size_t)l * G * H;
    const float* Whh = w_hh + (size_t)l * G * H;
    const float* bih = b_ih + (size_t)l * G;
    const float* bhh = b_hh + (size_t)l * G;
    const float* lwp = lnw + (size_t)l * 3 * H;
    const float* lbp = lnb + (size_t)l * 3 * H;
    const float* src = (l == 0) ? x : seq;
    const float* resp = (l == 0) ? x : seq;

    for (int c = 0; c < NCH; ++c) {
      int t0 = c * CHUNK;
      gemm_bt<<<dim3(G / 64, B), 256, 0, stream>>>(
          src + (size_t)t0 * H, (size_t)T * H, Wih, bih,
          xg, (size_t)CHUNK * G, CHUNK);
      const float* hin = (c == 0) ? (h0 + (size_t)l * B * H) : hstate;
      gru_chunk<<<NWG, 256, 0, stream>>>(
          Whh, bhh, lwp, lbp, xg, resp, seq, t0, CHUNK,
          hin, hstate, hbf, stats1, stats2,
          barctr + (size_t)(l * NCH + c) * 16,
          hfin + (size_t)l * B * H, (c == NCH - 1) ? 1 : 0);
    }
  }
}

// Round 3
// 17191.248 us; speedup vs baseline: 1.4346x; 1.4346x over previous
//
#include <hip/hip_runtime.h>

typedef short bf16x8 __attribute__((ext_vector_type(8)));
typedef float f32x4 __attribute__((ext_vector_type(4)));

__device__ __forceinline__ unsigned pack2bf(float a, float b) {
  union { float f; unsigned u; } x, y;
  x.f = a; y.f = b;
  unsigned ra = (x.u + 0x7FFFu + ((x.u >> 16) & 1u)) >> 16;
  unsigned rb = (y.u + 0x7FFFu + ((y.u >> 16) & 1u)) & 0xFFFF0000u;
  return ra | rb;
}
__device__ __forceinline__ unsigned short bfu(float f) {
  union { float f; unsigned u; } v; v.f = f;
  return (unsigned short)((v.u + 0x7FFFu + ((v.u >> 16) & 1u)) >> 16);
}
__device__ __forceinline__ float sigf(float x) { return 1.f / (1.f + __expf(-x)); }

#define KB 64
#define LDSP 72

// ---------------- xg GEMM (proven in rounds 1-2, cheap: ~0.7ms total) ----------------
__global__ __launch_bounds__(256) void gemm_bt(
    const float* __restrict__ A0, size_t a_bstride,
    const float* __restrict__ W,
    const float* __restrict__ bias,
    float* __restrict__ out, size_t o_bstride,
    int Mvalid)
{
  __shared__ unsigned short As[64][LDSP];
  __shared__ unsigned short Bs[64][LDSP];
  const int tid = threadIdx.x;
  const int g0 = blockIdx.x * 64;
  const float* Ab = A0 + (size_t)blockIdx.y * a_bstride;
  float* outb = out + (size_t)blockIdx.y * o_bstride;

  const int srow = tid >> 2;
  const int scol = (tid & 3) << 4;
  const int wv = tid >> 6;
  const int lane = tid & 63;
  const int wr = wv >> 1, wc = wv & 1;
  const int lrow = lane & 15;
  const int lk = (lane >> 4) << 3;

  f32x4 acc[2][2];
#pragma unroll
  for (int i = 0; i < 2; ++i)
#pragma unroll
    for (int j = 0; j < 2; ++j)
      acc[i][j] = (f32x4){0.f, 0.f, 0.f, 0.f};

  const float* Aptr = Ab + (size_t)srow * 768 + scol;
  const float* Bptr = W + ((size_t)(g0 + srow)) * 768 + scol;
  const bool aval = srow < Mvalid;

  for (int k0 = 0; k0 < 768; k0 += KB) {
    uint4 ua0, ua1, ub0, ub1;
    if (aval) {
      const float4* qa = (const float4*)(Aptr + k0);
      float4 f0 = qa[0], f1 = qa[1], f2 = qa[2], f3 = qa[3];
      ua0 = make_uint4(pack2bf(f0.x, f0.y), pack2bf(f0.z, f0.w),
                       pack2bf(f1.x, f1.y), pack2bf(f1.z, f1.w));
      ua1 = make_uint4(pack2bf(f2.x, f2.y), pack2bf(f2.z, f2.w),
                       pack2bf(f3.x, f3.y), pack2bf(f3.z, f3.w));
    } else {
      ua0 = make_uint4(0u, 0u, 0u, 0u);
      ua1 = ua0;
    }
    {
      const float4* qb = (const float4*)(Bptr + k0);
      float4 f0 = qb[0], f1 = qb[1], f2 = qb[2], f3 = qb[3];
      ub0 = make_uint4(pack2bf(f0.x, f0.y), pack2bf(f0.z, f0.w),
                       pack2bf(f1.x, f1.y), pack2bf(f1.z, f1.w));
      ub1 = make_uint4(pack2bf(f2.x, f2.y), pack2bf(f2.z, f2.w),
                       pack2bf(f3.x, f3.y), pack2bf(f3.z, f3.w));
    }
    __syncthreads();
    *(uint4*)&As[srow][scol] = ua0;
    *(uint4*)&As[srow][scol + 8] = ua1;
    *(uint4*)&Bs[srow][scol] = ub0;
    *(uint4*)&Bs[srow][scol + 8] = ub1;
    __syncthreads();
#pragma unroll
    for (int kh = 0; kh < 2; ++kh) {
      bf16x8 a0 = *(const bf16x8*)&As[32 * wr + lrow][32 * kh + lk];
      bf16x8 a1 = *(const bf16x8*)&As[32 * wr + 16 + lrow][32 * kh + lk];
      bf16x8 b0 = *(const bf16x8*)&Bs[32 * wc + lrow][32 * kh + lk];
      bf16x8 b1 = *(const bf16x8*)&Bs[32 * wc + 16 + lrow][32 * kh + lk];
      acc[0][0] = __builtin_amdgcn_mfma_f32_16x16x32_bf16(a0, b0, acc[0][0], 0, 0, 0);
      acc[0][1] = __builtin_amdgcn_mfma_f32_16x16x32_bf16(a0, b1, acc[0][1], 0, 0, 0);
      acc[1][0] = __builtin_amdgcn_mfma_f32_16x16x32_bf16(a1, b0, acc[1][0], 0, 0, 0);
      acc[1][1] = __builtin_amdgcn_mfma_f32_16x16x32_bf16(a1, b1, acc[1][1], 0, 0, 0);
    }
  }

  const int lgrp = lane >> 4;
#pragma unroll
  for (int fr = 0; fr < 2; ++fr)
#pragma unroll
    for (int fc = 0; fc < 2; ++fc)
#pragma unroll
      for (int j = 0; j < 4; ++j) {
        int m = 32 * wr + 16 * fr + lgrp * 4 + j;
        int n = 32 * wc + 16 * fc + lrow;
        if (m < Mvalid)
          outb[(size_t)m * 2304 + g0 + n] = acc[fr][fc][j] + bias[g0 + n];
      }
}

// ---------------- persistent recurrent kernel: 72 WGs, 2 barriers/step ----------------
#define NWG 72
#define EPS 1e-5f
#define INV768 (1.0f / 768.0f)

// arrive: MUST be preceded by __syncthreads (drains all waves' stores to L2);
// the RELEASE RMW emits one L2 writeback (wbl2) making our stores agent-visible.
__device__ __forceinline__ void bar_arrive(unsigned* c) {
  __syncthreads();
  if (threadIdx.x == 0)
    __hip_atomic_fetch_add(c + (blockIdx.x & 7) * 16, 1u,
                           __ATOMIC_RELEASE, __HIP_MEMORY_SCOPE_AGENT);
}
// wait: RELAXED spin (no cache maintenance per poll); one acquire (L2 inv) at exit.
// Sum of monotonically-increasing counters can only under-read -> exit is safe.
__device__ __forceinline__ void bar_wait(unsigned* c, unsigned tgt) {
  if (threadIdx.x == 0) {
    for (;;) {
      unsigned s = 0;
#pragma unroll
      for (int i = 0; i < 8; ++i)
        s += __hip_atomic_load(c + i * 16, __ATOMIC_RELAXED, __HIP_MEMORY_SCOPE_AGENT);
      if (s >= tgt) break;
      __builtin_amdgcn_s_sleep(2);
    }
  }
  __syncthreads();
  __builtin_amdgcn_fence(__ATOMIC_ACQUIRE, "agent");
}

template <int N>
__device__ __forceinline__ void blk_reduce(float* v, float* lds) {
#pragma unroll
  for (int k = 0; k < N; ++k) {
    float x = v[k];
#pragma unroll
    for (int off = 1; off < 64; off <<= 1) x += __shfl_xor(x, off);
    v[k] = x;
  }
  const int wv = threadIdx.x >> 6;
  const int lane = threadIdx.x & 63;
  if (lane == 0) {
#pragma unroll
    for (int k = 0; k < N; ++k) lds[wv * N + k] = v[k];
  }
  __syncthreads();
#pragma unroll
  for (int k = 0; k < N; ++k)
    v[k] = lds[k] + lds[N + k] + lds[2 * N + k] + lds[3 * N + k];
  __syncthreads();
}

__global__ __launch_bounds__(256, 1) void gru_chunk(
    const float* __restrict__ Whh, const float* __restrict__ bhh,
    const float* __restrict__ lw, const float* __restrict__ lb,
    const float* __restrict__ xg,     // [64][TC][2304]  (includes b_ih)
    const float* __restrict__ res,    // residual [64][512][768]
    float* __restrict__ seq,          // output seq [64][512][768]
    int t0, int TC,
    const float* __restrict__ hin,    // [64][768] f32
    float* __restrict__ hstate,       // [64][768] f32
    unsigned short* __restrict__ hbf, // tiled [96][64][8] bf16
    float* __restrict__ hg,           // [64][2304] f32 (includes b_hh)
    unsigned* __restrict__ barA, unsigned* __restrict__ barB,
    float* __restrict__ hfin, int lastflag)
{
  __shared__ unsigned short Wl[32][776];
  __shared__ float lwl[2304], lbl[2304];
  __shared__ float bhl[32];
  __shared__ float redl[16];

  const int wg = blockIdx.x;
  const int tid = threadIdx.x;
  const int g0w = wg * 32;           // this WG's 32 gate rows
  const int lane = tid & 63;
  const int w = tid >> 6;            // wave id: batch block 16w..16w+15
  const int la = lane & 15;
  const int kb = lane >> 4;          // k-block within K=32

  // ---- init: stage this WG's W_hh rows into LDS as bf16 ----
  for (int r = 0; r < 32; ++r) {
    const float* src = Whh + (size_t)(g0w + r) * 768;
    for (int c = tid; c < 768; c += 256) Wl[r][c] = bfu(src[c]);
  }
  if (tid < 32) bhl[tid] = bhh[g0w + tid];

  const int b = wg;                  // update-phase batch (only wg<64)
  float hreg[3] = {0.f, 0.f, 0.f};
  if (wg < 64) {
    for (int c = tid; c < 2304; c += 256) { lwl[c] = lw[c]; lbl[c] = lb[c]; }
#pragma unroll
    for (int p = 0; p < 3; ++p) hreg[p] = hin[(size_t)b * 768 + tid + (p << 8)];
    if (t0 == 0) {
#pragma unroll
      for (int p = 0; p < 3; ++p) {
        int i = tid + (p << 8);
        hbf[((i >> 3) * 64 + b) * 8 + (i & 7)] = bfu(hreg[p]);
      }
    }
  }
  bar_arrive(barB);
  bar_wait(barB, NWG);   // barB epoch 1: hbf initialized

  for (int tt = 0; tt < TC; ++tt) {
    // ---- phase A (all 72 WGs): hg[all b][our 32 rows] = h @ Whh^T + bhh ----
    f32x4 acc0 = (f32x4){0.f, 0.f, 0.f, 0.f}, acc1 = acc0;
#pragma unroll 6
    for (int kk = 0; kk < 24; ++kk) {
      bf16x8 af = *(const bf16x8*)(hbf + (size_t)(((kk * 4 + kb) * 64) + 16 * w + la) * 8);
      bf16x8 b0 = *(const bf16x8*)&Wl[la][kk * 32 + kb * 8];
      bf16x8 b1 = *(const bf16x8*)&Wl[16 + la][kk * 32 + kb * 8];
      acc0 = __builtin_amdgcn_mfma_f32_16x16x32_bf16(af, b0, acc0, 0, 0, 0);
      acc1 = __builtin_amdgcn_mfma_f32_16x16x32_bf16(af, b1, acc1, 0, 0, 0);
    }
#pragma unroll
    for (int j = 0; j < 4; ++j) {
      int bb = 16 * w + kb * 4 + j;      // C row = batch
      hg[(size_t)bb * 2304 + g0w + la]      = acc0[j] + bhl[la];
      hg[(size_t)bb * 2304 + g0w + 16 + la] = acc1[j] + bhl[16 + la];
    }
    bar_arrive(barA);
    bar_wait(barA, (unsigned)(tt + 1) * NWG);

    // ---- phase B (WGs 0-63): batch-owner LN + gate math + h update ----
    if (wg < 64) {
      const float* hgb = hg + (size_t)b * 2304;
      const float* xgb = xg + ((size_t)b * TC + tt) * 2304;
      float s1[3], s2[3], hn[3], xn[3];
      float v4[4] = {0.f, 0.f, 0.f, 0.f};
#pragma unroll
      for (int p = 0; p < 3; ++p) {
        int i = tid + (p << 8);
        s1[p] = hgb[i] + xgb[i];
        s2[p] = hgb[768 + i] + xgb[768 + i];
        hn[p] = hgb[1536 + i];
        xn[p] = xgb[1536 + i];
        v4[0] += s1[p]; v4[1] += s1[p] * s1[p];
        v4[2] += s2[p]; v4[3] += s2[p] * s2[p];
      }
      blk_reduce<4>(v4, redl);
      float mu1 = v4[0] * INV768, rs1 = rsqrtf(v4[1] * INV768 - mu1 * mu1 + EPS);
      float mu2 = v4[2] * INV768, rs2 = rsqrtf(v4[3] * INV768 - mu2 * mu2 + EPS);

      float zq[3], mq[3];
      float v2[2] = {0.f, 0.f};
#pragma unroll
      for (int p = 0; p < 3; ++p) {
        int i = tid + (p << 8);
        float r = sigf((s1[p] - mu1) * rs1 * lwl[i] + lbl[i]);
        zq[p] = sigf((s2[p] - mu2) * rs2 * lwl[768 + i] + lbl[768 + i]);
        mq[p] = xn[p] + r * hn[p];
        v2[0] += mq[p]; v2[1] += mq[p] * mq[p];
      }
      blk_reduce<2>(v2, redl);
      float mum = v2[0] * INV768, rsm = rsqrtf(v2[1] * INV768 - mum * mum + EPS);

      const int gt = t0 + tt;
#pragma unroll
      for (int p = 0; p < 3; ++p) {
        int i = tid + (p << 8);
        float n = tanhf((mq[p] - mum) * rsm * lwl[1536 + i] + lbl[1536 + i]);
        float hnew = (1.f - zq[p]) * n + zq[p] * hreg[p];
        hreg[p] = hnew;
        size_t o = ((size_t)b * 512 + gt) * 768 + i;
        float rv = res[o];
        seq[o] = hnew + rv;
        hbf[((i >> 3) * 64 + b) * 8 + (i & 7)] = bfu(hnew);
      }
    }
    bar_arrive(barB);
    bar_wait(barB, (unsigned)(tt + 2) * NWG);
  }

  if (wg < 64) {
#pragma unroll
    for (int p = 0; p < 3; ++p) {
      int i = tid + (p << 8);
      hstate[(size_t)b * 768 + i] = hreg[p];
      if (lastflag) hfin[(size_t)b * 768 + i] = hreg[p];
    }
  }
}

extern "C" void kernel_launch(void* const* d_in, const int* in_sizes, int n_in,
                              void* d_out, int out_size, void* d_ws, size_t ws_size,
                              hipStream_t stream) {
  const float* x    = (const float*)d_in[0];
  const float* h0   = (const float*)d_in[1];
  const float* w_ih = (const float*)d_in[2];
  const float* b_ih = (const float*)d_in[3];
  const float* w_hh = (const float*)d_in[4];
  const float* b_hh = (const float*)d_in[5];
  const float* lnw  = (const float*)d_in[6];
  const float* lnb  = (const float*)d_in[7];
  float* out = (float*)d_out;

  const int B = 64, T = 512, H = 768, G = 2304, L = 2;

  const size_t BAR_BYTES = 65536;
  const size_t fixed = BAR_BYTES + 98304 + 196608 + 589824;
  int CHUNK = 64;
  for (;;) {
    size_t need = fixed + (size_t)B * CHUNK * G * 4;
    if (need <= ws_size || CHUNK == 8) break;
    CHUNK >>= 1;
  }

  unsigned* barctr = (unsigned*)d_ws;
  unsigned short* hbf = (unsigned short*)((char*)d_ws + BAR_BYTES);
  float* hstate = (float*)((char*)d_ws + BAR_BYTES + 98304);
  float* hg     = hstate + 49152;
  float* xg     = hg + 147456;

  hipMemsetAsync(barctr, 0, BAR_BYTES, stream);

  float* seq  = out;
  float* hfin = out + (size_t)B * T * H;
  const int NCH = T / CHUNK;

  for (int l = 0; l < L; ++l) {
    const float* Wih = w_ih + (size_t)l * G * H;
    const float* Whh = w_hh + (size_t)l * G * H;
    const float* bih = b_ih + (size_t)l * G;
    const float* bhh = b_hh + (size_t)l * G;
    const float* lwp = lnw + (size_t)l * 3 * H;
    const float* lbp = lnb + (size_t)l * 3 * H;
    const float* src = (l == 0) ? x : seq;
    const float* resp = (l == 0) ? x : seq;

    for (int c = 0; c < NCH; ++c) {
      int t0 = c * CHUNK;
      gemm_bt<<<dim3(G / 64, B), 256, 0, stream>>>(
          src + (size_t)t0 * H, (size_t)T * H, Wih, bih,
          xg, (size_t)CHUNK * G, CHUNK);
      const float* hin = (c == 0) ? (h0 + (size_t)l * B * H) : hstate;
      unsigned* barA = barctr + (size_t)(l * NCH + c) * 256;
      unsigned* barB = barA + 128;
      gru_chunk<<<NWG, 256, 0, stream>>>(
          Whh, bhh, lwp, lbp, xg, resp, seq, t0, CHUNK,
          hin, hstate, hbf, hg, barA, barB,
          hfin + (size_t)l * B * H, (c == NCH - 1) ? 1 : 0);
    }
  }
}

// Round 4
// 11435.575 us; speedup vs baseline: 2.1566x; 1.5033x over previous
//
#include <hip/hip_runtime.h>

typedef short bf16x8 __attribute__((ext_vector_type(8)));
typedef float f32x4 __attribute__((ext_vector_type(4)));

__device__ __forceinline__ unsigned pack2bf(float a, float b) {
  union { float f; unsigned u; } x, y;
  x.f = a; y.f = b;
  unsigned ra = (x.u + 0x7FFFu + ((x.u >> 16) & 1u)) >> 16;
  unsigned rb = (y.u + 0x7FFFu + ((y.u >> 16) & 1u)) & 0xFFFF0000u;
  return ra | rb;
}
__device__ __forceinline__ unsigned short bfu(float f) {
  union { float f; unsigned u; } v; v.f = f;
  return (unsigned short)((v.u + 0x7FFFu + ((v.u >> 16) & 1u)) >> 16);
}
__device__ __forceinline__ float sigf(float x) { return 1.f / (1.f + __expf(-x)); }

#define KB 64
#define LDSP 72

// ---------------- xg GEMM (proven rounds 1-3) ----------------
__global__ __launch_bounds__(256) void gemm_bt(
    const float* __restrict__ A0, size_t a_bstride,
    const float* __restrict__ W,
    const float* __restrict__ bias,
    float* __restrict__ out, size_t o_bstride,
    int Mvalid)
{
  __shared__ unsigned short As[64][LDSP];
  __shared__ unsigned short Bs[64][LDSP];
  const int tid = threadIdx.x;
  const int g0 = blockIdx.x * 64;
  const float* Ab = A0 + (size_t)blockIdx.y * a_bstride;
  float* outb = out + (size_t)blockIdx.y * o_bstride;

  const int srow = tid >> 2;
  const int scol = (tid & 3) << 4;
  const int wv = tid >> 6;
  const int lane = tid & 63;
  const int wr = wv >> 1, wc = wv & 1;
  const int lrow = lane & 15;
  const int lk = (lane >> 4) << 3;

  f32x4 acc[2][2];
#pragma unroll
  for (int i = 0; i < 2; ++i)
#pragma unroll
    for (int j = 0; j < 2; ++j)
      acc[i][j] = (f32x4){0.f, 0.f, 0.f, 0.f};

  const float* Aptr = Ab + (size_t)srow * 768 + scol;
  const float* Bptr = W + ((size_t)(g0 + srow)) * 768 + scol;
  const bool aval = srow < Mvalid;

  for (int k0 = 0; k0 < 768; k0 += KB) {
    uint4 ua0, ua1, ub0, ub1;
    if (aval) {
      const float4* qa = (const float4*)(Aptr + k0);
      float4 f0 = qa[0], f1 = qa[1], f2 = qa[2], f3 = qa[3];
      ua0 = make_uint4(pack2bf(f0.x, f0.y), pack2bf(f0.z, f0.w),
                       pack2bf(f1.x, f1.y), pack2bf(f1.z, f1.w));
      ua1 = make_uint4(pack2bf(f2.x, f2.y), pack2bf(f2.z, f2.w),
                       pack2bf(f3.x, f3.y), pack2bf(f3.z, f3.w));
    } else {
      ua0 = make_uint4(0u, 0u, 0u, 0u);
      ua1 = ua0;
    }
    {
      const float4* qb = (const float4*)(Bptr + k0);
      float4 f0 = qb[0], f1 = qb[1], f2 = qb[2], f3 = qb[3];
      ub0 = make_uint4(pack2bf(f0.x, f0.y), pack2bf(f0.z, f0.w),
                       pack2bf(f1.x, f1.y), pack2bf(f1.z, f1.w));
      ub1 = make_uint4(pack2bf(f2.x, f2.y), pack2bf(f2.z, f2.w),
                       pack2bf(f3.x, f3.y), pack2bf(f3.z, f3.w));
    }
    __syncthreads();
    *(uint4*)&As[srow][scol] = ua0;
    *(uint4*)&As[srow][scol + 8] = ua1;
    *(uint4*)&Bs[srow][scol] = ub0;
    *(uint4*)&Bs[srow][scol + 8] = ub1;
    __syncthreads();
#pragma unroll
    for (int kh = 0; kh < 2; ++kh) {
      bf16x8 a0 = *(const bf16x8*)&As[32 * wr + lrow][32 * kh + lk];
      bf16x8 a1 = *(const bf16x8*)&As[32 * wr + 16 + lrow][32 * kh + lk];
      bf16x8 b0 = *(const bf16x8*)&Bs[32 * wc + lrow][32 * kh + lk];
      bf16x8 b1 = *(const bf16x8*)&Bs[32 * wc + 16 + lrow][32 * kh + lk];
      acc[0][0] = __builtin_amdgcn_mfma_f32_16x16x32_bf16(a0, b0, acc[0][0], 0, 0, 0);
      acc[0][1] = __builtin_amdgcn_mfma_f32_16x16x32_bf16(a0, b1, acc[0][1], 0, 0, 0);
      acc[1][0] = __builtin_amdgcn_mfma_f32_16x16x32_bf16(a1, b0, acc[1][0], 0, 0, 0);
      acc[1][1] = __builtin_amdgcn_mfma_f32_16x16x32_bf16(a1, b1, acc[1][1], 0, 0, 0);
    }
  }

  const int lgrp = lane >> 4;
#pragma unroll
  for (int fr = 0; fr < 2; ++fr)
#pragma unroll
    for (int fc = 0; fc < 2; ++fc)
#pragma unroll
      for (int j = 0; j < 4; ++j) {
        int m = 32 * wr + 16 * fr + lgrp * 4 + j;
        int n = 32 * wc + 16 * fc + lrow;
        if (m < Mvalid)
          outb[(size_t)m * 2304 + g0 + n] = acc[fr][fc][j] + bias[g0 + n];
      }
}

// ---------------- persistent recurrent kernel ----------------
// Cross-WG exchange via agent-scope relaxed atomics (coherence-point, sc1):
// no release fences (no L2 writeback storms); one acquire fence per step
// (only to let phase A read hbf with plain cached loads).
#define NWG 72
#define EPS 1e-5f
#define INV768 (1.0f / 768.0f)

__device__ __forceinline__ void bar_arrive(unsigned* c) {
  __syncthreads();  // emits s_waitcnt vmcnt(0): our sc1 stores are at IF before arrive
  if (threadIdx.x == 0)
    __hip_atomic_fetch_add(c + (blockIdx.x & 7) * 32, 1u,
                           __ATOMIC_RELAXED, __HIP_MEMORY_SCOPE_AGENT);
}
// Relaxed spin on 8 distributed monotone counters; sum can only under-read.
__device__ __forceinline__ void bar_wait(unsigned* c, unsigned tgt) {
  if (threadIdx.x == 0) {
    for (;;) {
      unsigned s = 0;
#pragma unroll
      for (int i = 0; i < 8; ++i)
        s += __hip_atomic_load(c + i * 32, __ATOMIC_RELAXED, __HIP_MEMORY_SCOPE_AGENT);
      if (s >= tgt) break;
      __builtin_amdgcn_s_sleep(2);
    }
  }
  __syncthreads();  // exec + compiler barrier for all threads
}

template <int N>
__device__ __forceinline__ void blk_reduce(float* v, float* lds) {
#pragma unroll
  for (int k = 0; k < N; ++k) {
    float x = v[k];
#pragma unroll
    for (int off = 1; off < 64; off <<= 1) x += __shfl_xor(x, off);
    v[k] = x;
  }
  const int wv = threadIdx.x >> 6;
  const int lane = threadIdx.x & 63;
  if (lane == 0) {
#pragma unroll
    for (int k = 0; k < N; ++k) lds[wv * N + k] = v[k];
  }
  __syncthreads();
#pragma unroll
  for (int k = 0; k < N; ++k)
    v[k] = lds[k] + lds[N + k] + lds[2 * N + k] + lds[3 * N + k];
  __syncthreads();
}

__global__ __launch_bounds__(256, 1) void gru_chunk(
    const float* __restrict__ Whh, const float* __restrict__ bhh,
    const float* __restrict__ lw, const float* __restrict__ lb,
    const float* __restrict__ xg,     // [64][TC][2304]  (includes b_ih)
    const float* __restrict__ res,    // residual [64][512][768]
    float* __restrict__ seq,          // output seq [64][512][768]
    int t0, int TC,
    const float* __restrict__ hin,    // [64][768] f32
    float* __restrict__ hstate,       // [64][768] f32
    unsigned* __restrict__ hbf32,     // [96][64][4] u32 (= bf16 pairs), sc1-only
    float* __restrict__ hg,           // [64][2304] f32, sc1-only
    unsigned* __restrict__ barA, unsigned* __restrict__ barB,
    float* __restrict__ hfin, int lastflag)
{
  __shared__ unsigned short Wl[32][776];
  __shared__ float lwl[2304], lbl[2304];
  __shared__ float bhl[32];
  __shared__ float redl[16];

  const int wg = blockIdx.x;
  const int tid = threadIdx.x;
  const int g0w = wg * 32;
  const int lane = tid & 63;
  const int w = tid >> 6;
  const int la = lane & 15;
  const int kb = lane >> 4;

  for (int r = 0; r < 32; ++r) {
    const float* src = Whh + (size_t)(g0w + r) * 768;
    for (int c = tid; c < 768; c += 256) Wl[r][c] = bfu(src[c]);
  }
  if (tid < 32) bhl[tid] = bhh[g0w + tid];

  const int b = wg;
  float hreg[3] = {0.f, 0.f, 0.f};
  if (wg < 64) {
    for (int c = tid; c < 2304; c += 256) { lwl[c] = lw[c]; lbl[c] = lb[c]; }
#pragma unroll
    for (int p = 0; p < 3; ++p) hreg[p] = hin[(size_t)b * 768 + tid + (p << 8)];
    if (t0 == 0) {
#pragma unroll
      for (int p = 0; p < 3; ++p) {
        int i = tid + (p << 8);
        float other = __shfl_xor(hreg[p], 1);
        if ((tid & 1) == 0) {
          unsigned pk = pack2bf(hreg[p], other);
          __hip_atomic_store(hbf32 + (i >> 3) * 256 + b * 4 + ((i >> 1) & 3), pk,
                             __ATOMIC_RELAXED, __HIP_MEMORY_SCOPE_AGENT);
        }
      }
    }
  }
  bar_arrive(barB);
  bar_wait(barB, NWG);

  for (int tt = 0; tt < TC; ++tt) {
    // one L2/L1 invalidate per step: makes hbf (sc1-written) safe for plain loads
    __builtin_amdgcn_fence(__ATOMIC_ACQUIRE, "agent");

    // ---- phase A (all 72 WGs): hg[all b][our 32 rows] = h @ Whh^T + bhh ----
    f32x4 acc0 = (f32x4){0.f, 0.f, 0.f, 0.f}, acc1 = acc0;
#pragma unroll 6
    for (int kk = 0; kk < 24; ++kk) {
      bf16x8 af = *(const bf16x8*)(hbf32 + (size_t)(((kk * 4 + kb) * 64) + 16 * w + la) * 4);
      bf16x8 b0 = *(const bf16x8*)&Wl[la][kk * 32 + kb * 8];
      bf16x8 b1 = *(const bf16x8*)&Wl[16 + la][kk * 32 + kb * 8];
      acc0 = __builtin_amdgcn_mfma_f32_16x16x32_bf16(af, b0, acc0, 0, 0, 0);
      acc1 = __builtin_amdgcn_mfma_f32_16x16x32_bf16(af, b1, acc1, 0, 0, 0);
    }
#pragma unroll
    for (int j = 0; j < 4; ++j) {
      int bb = 16 * w + kb * 4 + j;
      __hip_atomic_store(hg + (size_t)bb * 2304 + g0w + la, acc0[j] + bhl[la],
                         __ATOMIC_RELAXED, __HIP_MEMORY_SCOPE_AGENT);
      __hip_atomic_store(hg + (size_t)bb * 2304 + g0w + 16 + la, acc1[j] + bhl[16 + la],
                         __ATOMIC_RELAXED, __HIP_MEMORY_SCOPE_AGENT);
    }

    // hoist phase-B read-only loads (xg, res: prior-dispatch data) into regs
    float xr_[3], xz_[3], xn_[3], rv_[3];
    if (wg < 64) {
      const float* xgb = xg + ((size_t)b * TC + tt) * 2304;
#pragma unroll
      for (int p = 0; p < 3; ++p) {
        int i = tid + (p << 8);
        xr_[p] = xgb[i];
        xz_[p] = xgb[768 + i];
        xn_[p] = xgb[1536 + i];
        rv_[p] = res[((size_t)b * 512 + (t0 + tt)) * 768 + i];
      }
    }

    bar_arrive(barA);
    bar_wait(barA, (unsigned)(tt + 1) * NWG);

    // ---- phase B (WGs 0-63): batch-owner LN + gates + h update ----
    if (wg < 64) {
      const float* hgb = hg + (size_t)b * 2304;
      float s1[3], s2[3], hn[3];
      float v4[4] = {0.f, 0.f, 0.f, 0.f};
#pragma unroll
      for (int p = 0; p < 3; ++p) {
        int i = tid + (p << 8);
        float h_r = __hip_atomic_load(hgb + i, __ATOMIC_RELAXED, __HIP_MEMORY_SCOPE_AGENT);
        float h_z = __hip_atomic_load(hgb + 768 + i, __ATOMIC_RELAXED, __HIP_MEMORY_SCOPE_AGENT);
        hn[p] = __hip_atomic_load(hgb + 1536 + i, __ATOMIC_RELAXED, __HIP_MEMORY_SCOPE_AGENT);
        s1[p] = h_r + xr_[p];
        s2[p] = h_z + xz_[p];
        v4[0] += s1[p]; v4[1] += s1[p] * s1[p];
        v4[2] += s2[p]; v4[3] += s2[p] * s2[p];
      }
      blk_reduce<4>(v4, redl);
      float mu1 = v4[0] * INV768, rs1 = rsqrtf(v4[1] * INV768 - mu1 * mu1 + EPS);
      float mu2 = v4[2] * INV768, rs2 = rsqrtf(v4[3] * INV768 - mu2 * mu2 + EPS);

      float zq[3], mq[3];
      float v2[2] = {0.f, 0.f};
#pragma unroll
      for (int p = 0; p < 3; ++p) {
        int i = tid + (p << 8);
        float r = sigf((s1[p] - mu1) * rs1 * lwl[i] + lbl[i]);
        zq[p] = sigf((s2[p] - mu2) * rs2 * lwl[768 + i] + lbl[768 + i]);
        mq[p] = xn_[p] + r * hn[p];
        v2[0] += mq[p]; v2[1] += mq[p] * mq[p];
      }
      blk_reduce<2>(v2, redl);
      float mum = v2[0] * INV768, rsm = rsqrtf(v2[1] * INV768 - mum * mum + EPS);

      const int gt = t0 + tt;
#pragma unroll
      for (int p = 0; p < 3; ++p) {
        int i = tid + (p << 8);
        float n = tanhf((mq[p] - mum) * rsm * lwl[1536 + i] + lbl[1536 + i]);
        float hnew = (1.f - zq[p]) * n + zq[p] * hreg[p];
        hreg[p] = hnew;
        seq[((size_t)b * 512 + gt) * 768 + i] = hnew + rv_[p];
        float other = __shfl_xor(hnew, 1);
        if ((tid & 1) == 0) {
          unsigned pk = pack2bf(hnew, other);
          __hip_atomic_store(hbf32 + (i >> 3) * 256 + b * 4 + ((i >> 1) & 3), pk,
                             __ATOMIC_RELAXED, __HIP_MEMORY_SCOPE_AGENT);
        }
      }
    }
    bar_arrive(barB);
    bar_wait(barB, (unsigned)(tt + 2) * NWG);
  }

  if (wg < 64) {
#pragma unroll
    for (int p = 0; p < 3; ++p) {
      int i = tid + (p << 8);
      hstate[(size_t)b * 768 + i] = hreg[p];
      if (lastflag) hfin[(size_t)b * 768 + i] = hreg[p];
    }
  }
}

extern "C" void kernel_launch(void* const* d_in, const int* in_sizes, int n_in,
                              void* d_out, int out_size, void* d_ws, size_t ws_size,
                              hipStream_t stream) {
  const float* x    = (const float*)d_in[0];
  const float* h0   = (const float*)d_in[1];
  const float* w_ih = (const float*)d_in[2];
  const float* b_ih = (const float*)d_in[3];
  const float* w_hh = (const float*)d_in[4];
  const float* b_hh = (const float*)d_in[5];
  const float* lnw  = (const float*)d_in[6];
  const float* lnb  = (const float*)d_in[7];
  float* out = (float*)d_out;

  const int B = 64, T = 512, H = 768, G = 2304, L = 2;

  const size_t BAR_BYTES = 65536;
  const size_t fixed = BAR_BYTES + 98304 + 196608 + 589824;
  int CHUNK = 64;
  for (;;) {
    size_t need = fixed + (size_t)B * CHUNK * G * 4;
    if (need <= ws_size || CHUNK == 8) break;
    CHUNK >>= 1;
  }

  unsigned* barctr = (unsigned*)d_ws;
  unsigned* hbf32  = (unsigned*)((char*)d_ws + BAR_BYTES);
  float* hstate = (float*)((char*)d_ws + BAR_BYTES + 98304);
  float* hg     = hstate + 49152;
  float* xg     = hg + 147456;

  hipMemsetAsync(barctr, 0, BAR_BYTES, stream);

  float* seq  = out;
  float* hfin = out + (size_t)B * T * H;
  const int NCH = T / CHUNK;

  for (int l = 0; l < L; ++l) {
    const float* Wih = w_ih + (size_t)l * G * H;
    const float* Whh = w_hh + (size_t)l * G * H;
    const float* bih = b_ih + (size_t)l * G;
    const float* bhh = b_hh + (size_t)l * G;
    const float* lwp = lnw + (size_t)l * 3 * H;
    const float* lbp = lnb + (size_t)l * 3 * H;
    const float* src = (l == 0) ? x : seq;
    const float* resp = (l == 0) ? x : seq;

    for (int c = 0; c < NCH; ++c) {
      int t0 = c * CHUNK;
      gemm_bt<<<dim3(G / 64, B), 256, 0, stream>>>(
          src + (size_t)t0 * H, (size_t)T * H, Wih, bih,
          xg, (size_t)CHUNK * G, CHUNK);
      const float* hin = (c == 0) ? (h0 + (size_t)l * B * H) : hstate;
      unsigned* barA = barctr + (size_t)(l * NCH + c) * 1024;
      unsigned* barB = barA + 512;
      gru_chunk<<<NWG, 256, 0, stream>>>(
          Whh, bhh, lwp, lbp, xg, resp, seq, t0, CHUNK,
          hin, hstate, hbf32, hg, barA, barB,
          hfin + (size_t)l * B * H, (c == NCH - 1) ? 1 : 0);
    }
  }
}

// Round 5
// 9069.675 us; speedup vs baseline: 2.7192x; 1.2609x over previous
//
#include <hip/hip_runtime.h>

typedef short bf16x8 __attribute__((ext_vector_type(8)));
typedef float f32x4 __attribute__((ext_vector_type(4)));

__device__ __forceinline__ unsigned pack2bf(float a, float b) {
  union { float f; unsigned u; } x, y;
  x.f = a; y.f = b;
  unsigned ra = (x.u + 0x7FFFu + ((x.u >> 16) & 1u)) >> 16;
  unsigned rb = (y.u + 0x7FFFu + ((y.u >> 16) & 1u)) & 0xFFFF0000u;
  return ra | rb;
}
__device__ __forceinline__ unsigned short bfu(float f) {
  union { float f; unsigned u; } v; v.f = f;
  return (unsigned short)((v.u + 0x7FFFu + ((v.u >> 16) & 1u)) >> 16);
}
__device__ __forceinline__ float sigf(float x) { return 1.f / (1.f + __expf(-x)); }

#define KB 64
#define LDSP 72

// ---------------- xg GEMM (proven rounds 1-4) ----------------
__global__ __launch_bounds__(256) void gemm_bt(
    const float* __restrict__ A0, size_t a_bstride,
    const float* __restrict__ W,
    const float* __restrict__ bias,
    float* __restrict__ out, size_t o_bstride,
    int Mvalid)
{
  __shared__ unsigned short As[64][LDSP];
  __shared__ unsigned short Bs[64][LDSP];
  const int tid = threadIdx.x;
  const int g0 = blockIdx.x * 64;
  const float* Ab = A0 + (size_t)blockIdx.y * a_bstride;
  float* outb = out + (size_t)blockIdx.y * o_bstride;

  const int srow = tid >> 2;
  const int scol = (tid & 3) << 4;
  const int wv = tid >> 6;
  const int lane = tid & 63;
  const int wr = wv >> 1, wc = wv & 1;
  const int lrow = lane & 15;
  const int lk = (lane >> 4) << 3;

  f32x4 acc[2][2];
#pragma unroll
  for (int i = 0; i < 2; ++i)
#pragma unroll
    for (int j = 0; j < 2; ++j)
      acc[i][j] = (f32x4){0.f, 0.f, 0.f, 0.f};

  const float* Aptr = Ab + (size_t)srow * 768 + scol;
  const float* Bptr = W + ((size_t)(g0 + srow)) * 768 + scol;
  const bool aval = srow < Mvalid;

  for (int k0 = 0; k0 < 768; k0 += KB) {
    uint4 ua0, ua1, ub0, ub1;
    if (aval) {
      const float4* qa = (const float4*)(Aptr + k0);
      float4 f0 = qa[0], f1 = qa[1], f2 = qa[2], f3 = qa[3];
      ua0 = make_uint4(pack2bf(f0.x, f0.y), pack2bf(f0.z, f0.w),
                       pack2bf(f1.x, f1.y), pack2bf(f1.z, f1.w));
      ua1 = make_uint4(pack2bf(f2.x, f2.y), pack2bf(f2.z, f2.w),
                       pack2bf(f3.x, f3.y), pack2bf(f3.z, f3.w));
    } else {
      ua0 = make_uint4(0u, 0u, 0u, 0u);
      ua1 = ua0;
    }
    {
      const float4* qb = (const float4*)(Bptr + k0);
      float4 f0 = qb[0], f1 = qb[1], f2 = qb[2], f3 = qb[3];
      ub0 = make_uint4(pack2bf(f0.x, f0.y), pack2bf(f0.z, f0.w),
                       pack2bf(f1.x, f1.y), pack2bf(f1.z, f1.w));
      ub1 = make_uint4(pack2bf(f2.x, f2.y), pack2bf(f2.z, f2.w),
                       pack2bf(f3.x, f3.y), pack2bf(f3.z, f3.w));
    }
    __syncthreads();
    *(uint4*)&As[srow][scol] = ua0;
    *(uint4*)&As[srow][scol + 8] = ua1;
    *(uint4*)&Bs[srow][scol] = ub0;
    *(uint4*)&Bs[srow][scol + 8] = ub1;
    __syncthreads();
#pragma unroll
    for (int kh = 0; kh < 2; ++kh) {
      bf16x8 a0 = *(const bf16x8*)&As[32 * wr + lrow][32 * kh + lk];
      bf16x8 a1 = *(const bf16x8*)&As[32 * wr + 16 + lrow][32 * kh + lk];
      bf16x8 b0 = *(const bf16x8*)&Bs[32 * wc + lrow][32 * kh + lk];
      bf16x8 b1 = *(const bf16x8*)&Bs[32 * wc + 16 + lrow][32 * kh + lk];
      acc[0][0] = __builtin_amdgcn_mfma_f32_16x16x32_bf16(a0, b0, acc[0][0], 0, 0, 0);
      acc[0][1] = __builtin_amdgcn_mfma_f32_16x16x32_bf16(a0, b1, acc[0][1], 0, 0, 0);
      acc[1][0] = __builtin_amdgcn_mfma_f32_16x16x32_bf16(a1, b0, acc[1][0], 0, 0, 0);
      acc[1][1] = __builtin_amdgcn_mfma_f32_16x16x32_bf16(a1, b1, acc[1][1], 0, 0, 0);
    }
  }

  const int lgrp = lane >> 4;
#pragma unroll
  for (int fr = 0; fr < 2; ++fr)
#pragma unroll
    for (int fc = 0; fc < 2; ++fc)
#pragma unroll
      for (int j = 0; j < 4; ++j) {
        int m = 32 * wr + 16 * fr + lgrp * 4 + j;
        int n = 32 * wc + 16 * fc + lrow;
        if (m < Mvalid)
          outb[(size_t)m * 2304 + g0 + n] = acc[fr][fc][j] + bias[g0 + n];
      }
}

// ---------------- persistent recurrent kernel ----------------
// Cross-WG data moves exclusively via sc0|sc1 (coherence-point) wide
// loads/stores: no fences, no L2 invalidates, no HBM stores in the loop.
#define NWG 64
#define NPROD 36
#define EPS 1e-5f
#define INV768 (1.0f / 768.0f)
#define SLOT 24576u  // u32 words per h-history slot (96*64*4)

__device__ __forceinline__ void bar_arrive(unsigned* c) {
  __syncthreads();  // drains vmcnt: our sc1 stores are at the coherence point
  if (threadIdx.x == 0)
    __hip_atomic_fetch_add(c + (blockIdx.x & 7) * 32, 1u,
                           __ATOMIC_RELAXED, __HIP_MEMORY_SCOPE_AGENT);
}
__device__ __forceinline__ void bar_wait(unsigned* c, unsigned tgt) {
  if (threadIdx.x == 0) {
    for (;;) {
      unsigned s = 0;
#pragma unroll
      for (int i = 0; i < 8; ++i)
        s += __hip_atomic_load(c + i * 32, __ATOMIC_RELAXED, __HIP_MEMORY_SCOPE_AGENT);
      if (s >= tgt) break;
      __builtin_amdgcn_s_sleep(2);
    }
  }
  __syncthreads();
}

template <int N>
__device__ __forceinline__ void blk_reduce(float* v, float* lds) {
#pragma unroll
  for (int k = 0; k < N; ++k) {
    float x = v[k];
#pragma unroll
    for (int off = 1; off < 64; off <<= 1) x += __shfl_xor(x, off);
    v[k] = x;
  }
  const int wv = threadIdx.x >> 6;
  const int lane = threadIdx.x & 63;
  if (lane == 0) {
#pragma unroll
    for (int k = 0; k < N; ++k) lds[wv * N + k] = v[k];
  }
  __syncthreads();
#pragma unroll
  for (int k = 0; k < N; ++k)
    v[k] = lds[k] + lds[N + k] + lds[2 * N + k] + lds[3 * N + k];
  __syncthreads();
}

#define LD6(buf, kk0) \
  { _Pragma("unroll") for (int q_ = 0; q_ < 6; ++q_) { \
      const unsigned* p_ = hb + (size_t)((kk0) + q_) * 1024u; \
      asm volatile("global_load_dwordx4 %0, %1, off sc0 sc1" : "=v"(buf[q_]) : "v"(p_)); } }

#define WAITV(n) do { asm volatile("s_waitcnt vmcnt(" #n ")" ::: "memory"); \
                      __builtin_amdgcn_sched_barrier(0); } while (0)

#define MFMA6(buf, kk0) \
  { _Pragma("unroll") for (int q_ = 0; q_ < 6; ++q_) { \
      int kk_ = (kk0) + q_; \
      bf16x8 w0 = *(const bf16x8*)&Wl[la][kk_ * 32 + kb * 8]; \
      bf16x8 w1 = *(const bf16x8*)&Wl[16 + la][kk_ * 32 + kb * 8]; \
      bf16x8 w2 = *(const bf16x8*)&Wl[32 + la][kk_ * 32 + kb * 8]; \
      bf16x8 w3 = *(const bf16x8*)&Wl[48 + la][kk_ * 32 + kb * 8]; \
      acc0 = __builtin_amdgcn_mfma_f32_16x16x32_bf16(buf[q_], w0, acc0, 0, 0, 0); \
      acc1 = __builtin_amdgcn_mfma_f32_16x16x32_bf16(buf[q_], w1, acc1, 0, 0, 0); \
      acc2 = __builtin_amdgcn_mfma_f32_16x16x32_bf16(buf[q_], w2, acc2, 0, 0, 0); \
      acc3 = __builtin_amdgcn_mfma_f32_16x16x32_bf16(buf[q_], w3, acc3, 0, 0, 0); } }

__global__ __launch_bounds__(256, 1) void gru_chunk(
    const float* __restrict__ Whh, const float* __restrict__ bhh,
    const float* __restrict__ lw, const float* __restrict__ lb,
    const float* __restrict__ xg,     // [64][TC][2304]  (includes b_ih)
    int TC,
    const float* __restrict__ hin,    // [64][768] f32
    float* __restrict__ hstate,       // [64][768] f32
    unsigned* __restrict__ hbf32,     // [TC+1][96][64][4] u32 (bf16 pairs)
    float* __restrict__ hg,           // [64][2304] f32
    unsigned* __restrict__ barA, unsigned* __restrict__ barB,
    float* __restrict__ hfin, int lastflag)
{
  __shared__ unsigned short Wl[64][776];   // 64 gate rows (producers only)
  __shared__ float lwl[2304], lbl[2304];
  __shared__ float bhl[64];
  __shared__ float redl[16];
  __shared__ __align__(16) float hgl[2304];

  const int wg = blockIdx.x;
  const int tid = threadIdx.x;
  const int g0w = wg * 64;           // producer's 64 gate rows (wg < NPROD)
  const int lane = tid & 63;
  const int w = tid >> 6;            // wave: batches 16w..16w+15
  const int la = lane & 15;
  const int kb = lane >> 4;
  const int arow = 16 * w + la;

  if (wg < NPROD) {
    for (int r = 0; r < 64; ++r) {
      const float* src = Whh + (size_t)(g0w + r) * 768;
      for (int c = tid; c < 768; c += 256) Wl[r][c] = bfu(src[c]);
    }
    if (tid < 64) bhl[tid] = bhh[g0w + tid];
  }

  const int b = wg;                  // every WG owns batch b's update
  for (int c = tid; c < 2304; c += 256) { lwl[c] = lw[c]; lbl[c] = lb[c]; }
  float hreg[3];
#pragma unroll
  for (int p = 0; p < 3; ++p) hreg[p] = hin[(size_t)b * 768 + tid + (p << 8)];
  {
    // write h-history slot 0 (chunk's input state) as packed bf16
#pragma unroll
    for (int p = 0; p < 3; ++p) {
      int i = tid + (p << 8);
      float other = __shfl_xor(hreg[p], 1);
      if ((tid & 1) == 0) {
        unsigned pk = pack2bf(hreg[p], other);
        __hip_atomic_store(hbf32 + (i >> 3) * 256 + b * 4 + ((i >> 1) & 3), pk,
                           __ATOMIC_RELAXED, __HIP_MEMORY_SCOPE_AGENT);
      }
    }
  }
  bar_arrive(barB);
  bar_wait(barB, NWG);

  for (int tt = 0; tt < TC; ++tt) {
    // ---- phase A (producers): hg[all b][our 64 rows] = h @ Whh^T + bhh ----
    if (wg < NPROD) {
      const unsigned* hb = hbf32 + (size_t)tt * SLOT + (size_t)((kb * 64 + arow) << 2);
      f32x4 acc0 = (f32x4){0.f, 0.f, 0.f, 0.f}, acc1 = acc0, acc2 = acc0, acc3 = acc0;
      bf16x8 afA[6], afB[6];
      LD6(afA, 0);
      LD6(afB, 6);
      WAITV(6);
      MFMA6(afA, 0);
      LD6(afA, 12);
      WAITV(6);
      MFMA6(afB, 6);
      LD6(afB, 18);
      WAITV(6);
      MFMA6(afA, 12);
      WAITV(0);
      MFMA6(afB, 18);
#pragma unroll
      for (int j = 0; j < 4; ++j) {
        int bb = 16 * w + kb * 4 + j;
        float* hp = hg + (size_t)bb * 2304 + g0w;
        __hip_atomic_store(hp + la,      acc0[j] + bhl[la],      __ATOMIC_RELAXED, __HIP_MEMORY_SCOPE_AGENT);
        __hip_atomic_store(hp + 16 + la, acc1[j] + bhl[16 + la], __ATOMIC_RELAXED, __HIP_MEMORY_SCOPE_AGENT);
        __hip_atomic_store(hp + 32 + la, acc2[j] + bhl[32 + la], __ATOMIC_RELAXED, __HIP_MEMORY_SCOPE_AGENT);
        __hip_atomic_store(hp + 48 + la, acc3[j] + bhl[48 + la], __ATOMIC_RELAXED, __HIP_MEMORY_SCOPE_AGENT);
      }
    }

    // hoist xg loads (prior-dispatch data, plain cached)
    float xr_[3], xz_[3], xn_[3];
    {
      const float* xgb = xg + ((size_t)b * TC + tt) * 2304;
#pragma unroll
      for (int p = 0; p < 3; ++p) {
        int i = tid + (p << 8);
        xr_[p] = xgb[i];
        xz_[p] = xgb[768 + i];
        xn_[p] = xgb[1536 + i];
      }
    }

    bar_arrive(barA);
    bar_wait(barA, (unsigned)(tt + 1) * NWG);

    // ---- phase B (all 64 WGs): stage hg[b] via sc1 vector loads -> LDS ----
    {
      const float* hgb = hg + (size_t)b * 2304;
      f32x4 g0v, g1v; float g2v;
      const float* p0 = hgb + tid * 8;
      const float* p1 = p0 + 4;
      const float* p2 = hgb + 2048 + tid;
      asm volatile("global_load_dwordx4 %0, %1, off sc0 sc1" : "=v"(g0v) : "v"(p0));
      asm volatile("global_load_dwordx4 %0, %1, off sc0 sc1" : "=v"(g1v) : "v"(p1));
      asm volatile("global_load_dword %0, %1, off sc0 sc1" : "=v"(g2v) : "v"(p2));
      WAITV(0);
      *(f32x4*)&hgl[tid * 8] = g0v;
      *(f32x4*)&hgl[tid * 8 + 4] = g1v;
      hgl[2048 + tid] = g2v;
    }
    __syncthreads();

    {
      float s1[3], s2[3], hn[3];
      float v4[4] = {0.f, 0.f, 0.f, 0.f};
#pragma unroll
      for (int p = 0; p < 3; ++p) {
        int i = tid + (p << 8);
        s1[p] = hgl[i] + xr_[p];
        s2[p] = hgl[768 + i] + xz_[p];
        hn[p] = hgl[1536 + i];
        v4[0] += s1[p]; v4[1] += s1[p] * s1[p];
        v4[2] += s2[p]; v4[3] += s2[p] * s2[p];
      }
      blk_reduce<4>(v4, redl);
      float mu1 = v4[0] * INV768, rs1 = rsqrtf(v4[1] * INV768 - mu1 * mu1 + EPS);
      float mu2 = v4[2] * INV768, rs2 = rsqrtf(v4[3] * INV768 - mu2 * mu2 + EPS);

      float zq[3], mq[3];
      float v2[2] = {0.f, 0.f};
#pragma unroll
      for (int p = 0; p < 3; ++p) {
        int i = tid + (p << 8);
        float r = sigf((s1[p] - mu1) * rs1 * lwl[i] + lbl[i]);
        zq[p] = sigf((s2[p] - mu2) * rs2 * lwl[768 + i] + lbl[768 + i]);
        mq[p] = xn_[p] + r * hn[p];
        v2[0] += mq[p]; v2[1] += mq[p] * mq[p];
      }
      blk_reduce<2>(v2, redl);
      float mum = v2[0] * INV768, rsm = rsqrtf(v2[1] * INV768 - mum * mum + EPS);

      unsigned* hbslot = hbf32 + (size_t)(tt + 1) * SLOT;
#pragma unroll
      for (int p = 0; p < 3; ++p) {
        int i = tid + (p << 8);
        float n = tanhf((mq[p] - mum) * rsm * lwl[1536 + i] + lbl[1536 + i]);
        float hnew = (1.f - zq[p]) * n + zq[p] * hreg[p];
        hreg[p] = hnew;
        float other = __shfl_xor(hnew, 1);
        if ((tid & 1) == 0) {
          unsigned pk = pack2bf(hnew, other);
          __hip_atomic_store(hbslot + (i >> 3) * 256 + b * 4 + ((i >> 1) & 3), pk,
                             __ATOMIC_RELAXED, __HIP_MEMORY_SCOPE_AGENT);
        }
      }
    }
    bar_arrive(barB);
    bar_wait(barB, (unsigned)(tt + 2) * NWG);
  }

#pragma unroll
  for (int p = 0; p < 3; ++p) {
    int i = tid + (p << 8);
    hstate[(size_t)b * 768 + i] = hreg[p];
    if (lastflag) hfin[(size_t)b * 768 + i] = hreg[p];
  }
}

// ---------------- seq emission: seq = bf16(h_hist) + res ----------------
__global__ __launch_bounds__(256) void seq_emit(
    const unsigned* __restrict__ hbf,  // [TC+1][24576], slots 1..TC
    const float* __restrict__ res,
    float* __restrict__ seq,
    int t0, int TC)
{
  int t = blockIdx.x * 256 + threadIdx.x;   // [TC][64][96][4]
  int tt = t / 24576;
  int r = t % 24576;
  int b = r / 384;
  int r3 = r % 384;
  int blk = r3 >> 2;
  int q = r3 & 3;
  unsigned wv = hbf[(size_t)(tt + 1) * SLOT + (size_t)blk * 256 + b * 4 + q];
  int i = blk * 8 + q * 2;
  size_t o = ((size_t)b * 512 + t0 + tt) * 768 + i;
  float lo = __uint_as_float(wv << 16);
  float hi = __uint_as_float(wv & 0xFFFF0000u);
  float2 rv = *(const float2*)(res + o);
  float2 ov = make_float2(lo + rv.x, hi + rv.y);
  *(float2*)(seq + o) = ov;
}

extern "C" void kernel_launch(void* const* d_in, const int* in_sizes, int n_in,
                              void* d_out, int out_size, void* d_ws, size_t ws_size,
                              hipStream_t stream) {
  const float* x    = (const float*)d_in[0];
  const float* h0   = (const float*)d_in[1];
  const float* w_ih = (const float*)d_in[2];
  const float* b_ih = (const float*)d_in[3];
  const float* w_hh = (const float*)d_in[4];
  const float* b_hh = (const float*)d_in[5];
  const float* lnw  = (const float*)d_in[6];
  const float* lnb  = (const float*)d_in[7];
  float* out = (float*)d_out;

  const int B = 64, T = 512, H = 768, G = 2304, L = 2;

  const size_t BAR = 1u << 20;
  int CHUNK = 64;
  for (;;) {
    size_t need = BAR + ((size_t)CHUNK + 1) * 98304 + 196608 + 589824
                + (size_t)B * CHUNK * G * 4;
    if (need <= ws_size || CHUNK == 8) break;
    CHUNK >>= 1;
  }

  unsigned* barctr = (unsigned*)d_ws;
  unsigned* hbf32  = (unsigned*)((char*)d_ws + BAR);
  float* hstate = (float*)((char*)hbf32 + ((size_t)CHUNK + 1) * 98304);
  float* hg     = hstate + 49152;
  float* xg     = hg + 147456;

  hipMemsetAsync(barctr, 0, BAR, stream);

  float* seq  = out;
  float* hfin = out + (size_t)B * T * H;
  const int NCH = T / CHUNK;

  for (int l = 0; l < L; ++l) {
    const float* Wih = w_ih + (size_t)l * G * H;
    const float* Whh = w_hh + (size_t)l * G * H;
    const float* bih = b_ih + (size_t)l * G;
    const float* bhh = b_hh + (size_t)l * G;
    const float* lwp = lnw + (size_t)l * 3 * H;
    const float* lbp = lnb + (size_t)l * 3 * H;
    const float* src = (l == 0) ? x : seq;
    const float* resp = (l == 0) ? x : seq;

    for (int c = 0; c < NCH; ++c) {
      int t0 = c * CHUNK;
      gemm_bt<<<dim3(G / 64, B), 256, 0, stream>>>(
          src + (size_t)t0 * H, (size_t)T * H, Wih, bih,
          xg, (size_t)CHUNK * G, CHUNK);
      const float* hin = (c == 0) ? (h0 + (size_t)l * B * H) : hstate;
      unsigned* barA = barctr + (size_t)(l * NCH + c) * 1024;
      unsigned* barB = barA + 512;
      gru_chunk<<<NWG, 256, 0, stream>>>(
          Whh, bhh, lwp, lbp, xg, CHUNK,
          hin, hstate, hbf32, hg, barA, barB,
          hfin + (size_t)l * B * H, (c == NCH - 1) ? 1 : 0);
      seq_emit<<<CHUNK * 96, 256, 0, stream>>>(hbf32, resp, seq, t0, CHUNK);
    }
  }
}